// Round 7
// baseline (171.971 us; speedup 1.0000x reference)
//
#include <hip/hip_runtime.h>

// crop_and_resize (RoIAlign-style bilinear), fp32, NHWC.
// feats: (8, 64, 64, 256) fp32 = 4 MiB/image; boxes: (4000,4); box_ind: (4000,)
// out:   (4000, 7, 7, 256) fp32
//
// R7 DIAGNOSTIC: exact R4-best kernel (XCD partition, 2 cells/iter, nt
// stores) but the crop loop runs REPEAT=3 times (idempotent stores, memory
// barrier between reps prevents CSE). Purpose: make the crop dispatch ~210us
// so it tops the rocprof table and we finally see ITS counters instead of
// the harness fills. Rates (hbm_gbps, VALUBusy, Occupancy) are unchanged by
// repetition; FETCH/WRITE are 3x single-pass.

#define H 64
#define W 64
#define C 256
#define CROP_HW 49  // 7*7
#define NIMG 8
#define REPEAT 3

typedef float f32x4 __attribute__((ext_vector_type(4)));

// ---- kernel 1: stable bucket of box indices by image ----------------------
__global__ __launch_bounds__(512) void bucket_kernel(
    const int* __restrict__ box_ind,
    int* __restrict__ order,     // [n] box ids grouped by image (stable)
    int* __restrict__ offsets,   // [9] bucket offsets
    int n)
{
    const int wave = threadIdx.x >> 6;   // 0..7 == image id
    const int lane = threadIdx.x & 63;
    __shared__ int counts[NIMG];

    int cnt = 0;
    for (int i = lane; i < n; i += 64)
        cnt += (box_ind[i] == wave);
    for (int off = 32; off; off >>= 1)
        cnt += __shfl_down(cnt, off);
    if (lane == 0) counts[wave] = cnt;
    __syncthreads();

    int start = 0;
    for (int i = 0; i < wave; ++i) start += counts[i];
    if (threadIdx.x == 0) {
        int acc = 0;
        for (int i = 0; i < NIMG; ++i) { offsets[i] = acc; acc += counts[i]; }
        offsets[NIMG] = acc;
    }

    int pos = start;
    for (int base = 0; base < n; base += 64) {
        const int i = base + lane;
        const bool m = (i < n) && (box_ind[i] == wave);
        const unsigned long long mask = __ballot(m);
        const int below = __popcll(mask & ((1ULL << lane) - 1ULL));
        if (m) order[pos + below] = i;
        pos += __popcll(mask);
    }
}

// ---- per-cell geometry ------------------------------------------------------
struct Cell {
    int i00, i01, i10, i11;   // float4-granular feats indices (within image)
    float wx, wy;
    bool valid;
    size_t oidx;              // float4-granular output index (without lane)
};

__device__ __forceinline__ Cell cell_info(
    int c, const int* __restrict__ order, const f32x4* __restrict__ boxes4,
    int start, int lane)
{
    Cell k;
    const int bi = c / CROP_HW;
    const int r  = c - bi * CROP_HW;
    const int iy = r / 7;
    const int ix = r - iy * 7;
    const int b  = order[start + bi];

    const f32x4 bx = boxes4[b];   // {y1, x1, y2, x2} in one dwordx4

    // reference order: step = (hi-lo)*(extent-1)/(n-1); s = lo*(extent-1)+i*step
    const float stepy = (bx.z - bx.x) * 63.0f / 6.0f;
    const float stepx = (bx.w - bx.y) * 63.0f / 6.0f;
    const float ys = bx.x * 63.0f + (float)iy * stepy;
    const float xs = bx.y * 63.0f + (float)ix * stepx;

    const float y0f = floorf(ys);
    const float x0f = floorf(xs);
    k.wy = ys - y0f;
    k.wx = xs - x0f;

    const int y0 = min(max((int)y0f, 0), H - 1);
    const int y1 = min(y0 + 1, H - 1);
    const int x0 = min(max((int)x0f, 0), W - 1);
    const int x1 = min(x0 + 1, W - 1);

    k.valid = (ys >= 0.0f) && (ys <= (float)(H - 1)) &&
              (xs >= 0.0f) && (xs <= (float)(W - 1));

    k.i00 = (y0 * W + x0) * (C / 4) + lane;
    k.i01 = (y0 * W + x1) * (C / 4) + lane;
    k.i10 = (y1 * W + x0) * (C / 4) + lane;
    k.i11 = (y1 * W + x1) * (C / 4) + lane;

    k.oidx = (size_t)b * CROP_HW * (C / 4) + (size_t)r * (C / 4);
    return k;
}

__device__ __forceinline__ f32x4 lerp2(const f32x4& v00, const f32x4& v01,
                                       const f32x4& v10, const f32x4& v11,
                                       float wx, float wy, bool valid)
{
    const f32x4 top = v00 + (v01 - v00) * wx;
    const f32x4 bot = v10 + (v11 - v10) * wx;
    f32x4 res = top + (bot - top) * wy;
    if (!valid) res = (f32x4)0.0f;
    return res;
}

// ---- kernel 2: bilinear crop, XCD-partitioned, 2 cells/iter, nt stores ----
__global__ __launch_bounds__(256) void crop_resize_xcd(
    const float* __restrict__ feats,
    const float* __restrict__ boxes,
    const int*   __restrict__ order,
    const int*   __restrict__ offsets,
    float*       __restrict__ out)
{
    const int img  = blockIdx.x & 7;     // block->XCD round-robin heuristic
    const int slot = blockIdx.x >> 3;
    const int lane = threadIdx.x & 63;
    const int wv   = threadIdx.x >> 6;   // 0..3

    const int start  = offsets[img];
    const int nb     = offsets[img + 1] - start;
    const int ncells = nb * CROP_HW;
    const int npairs = (ncells + 1) >> 1;
    const int wave_local = slot * 4 + wv;
    const int stride     = (gridDim.x >> 3) * 4;

    const f32x4* __restrict__ f4 = reinterpret_cast<const f32x4*>(feats)
                                   + (size_t)img * (H * W * (C / 4));
    const f32x4* __restrict__ boxes4 = reinterpret_cast<const f32x4*>(boxes);
    f32x4* __restrict__ o4 = reinterpret_cast<f32x4*>(out);

    for (int rep = 0; rep < REPEAT; ++rep) {
        // stop the compiler from CSE-ing identical repetitions (restrict
        // would otherwise allow it); stores are idempotent so output is
        // unchanged.
        asm volatile("" ::: "memory");

        for (int p = wave_local; p < npairs; p += stride) {
            const int  c0    = p * 2;
            const bool haveB = (c0 + 1 < ncells);          // wave-uniform
            const int  c1    = haveB ? c0 + 1 : c0;

            const Cell a  = cell_info(c0, order, boxes4, start, lane);
            const Cell bb = cell_info(c1, order, boxes4, start, lane);

            // issue all 8 gathers before any lerp
            const f32x4 a00 = f4[a.i00];
            const f32x4 a01 = f4[a.i01];
            const f32x4 a10 = f4[a.i10];
            const f32x4 a11 = f4[a.i11];
            const f32x4 b00 = f4[bb.i00];
            const f32x4 b01 = f4[bb.i01];
            const f32x4 b10 = f4[bb.i10];
            const f32x4 b11 = f4[bb.i11];

            const f32x4 resA = lerp2(a00, a01, a10, a11, a.wx, a.wy, a.valid);
            __builtin_nontemporal_store(resA, &o4[a.oidx + lane]);

            if (haveB) {
                const f32x4 resB = lerp2(b00, b01, b10, b11, bb.wx, bb.wy, bb.valid);
                __builtin_nontemporal_store(resB, &o4[bb.oidx + lane]);
            }
        }
    }
}

extern "C" void kernel_launch(void* const* d_in, const int* in_sizes, int n_in,
                              void* d_out, int out_size, void* d_ws, size_t ws_size,
                              hipStream_t stream) {
    const float* feats   = (const float*)d_in[0];
    const float* boxes   = (const float*)d_in[1];
    const int*   box_ind = (const int*)d_in[2];
    float*       out     = (float*)d_out;

    const int n_boxes = in_sizes[1] / 4;

    int* order   = (int*)d_ws;            // n_boxes ints
    int* offsets = order + n_boxes;       // 9 ints

    bucket_kernel<<<1, 512, 0, stream>>>(box_ind, order, offsets, n_boxes);

    // 2048 blocks x 256 threads; 256 blocks (1024 waves) per image.
    crop_resize_xcd<<<2048, 256, 0, stream>>>(feats, boxes, order, offsets, out);
}

// Round 8
// 70.385 us; speedup vs baseline: 2.4433x; 2.4433x over previous
//
#include <hip/hip_runtime.h>

// crop_and_resize (RoIAlign-style bilinear), fp32, NHWC.
// feats: (8, 64, 64, 256) fp32 = 4 MiB/image; boxes: (4000,4); box_ind: (4000,)
// out:   (4000, 7, 7, 256) fp32
//
// R8: attack the 55% VALUBusy found by the R7 diagnostic. Geometry is
// wave-uniform per cell, so compute it LANE-PARALLEL: per 8-cell group,
// lane l computes the Cell for cell base+(l&7) (geometry cost /8), then an
// unrolled loop broadcasts each cell's params to SGPRs (v_readlane/ballot)
// and gathers with wave-uniform base + lane*16 (saddr). 4-weight FMA lerp.
// XCD partition (fetch 17.6 MB/rep measured) + nt stores kept.

#define H 64
#define W 64
#define C 256
#define CROP_HW 49  // 7*7
#define NIMG 8
#define G 8         // cells per wave-group (lane-parallel geometry)

typedef float f32x4 __attribute__((ext_vector_type(4)));

// ---- kernel 1: stable bucket of box indices by image ----------------------
__global__ __launch_bounds__(512) void bucket_kernel(
    const int* __restrict__ box_ind,
    int* __restrict__ order,     // [n] box ids grouped by image (stable)
    int* __restrict__ offsets,   // [9] bucket offsets
    int n)
{
    const int wave = threadIdx.x >> 6;   // 0..7 == image id
    const int lane = threadIdx.x & 63;
    __shared__ int counts[NIMG];

    int cnt = 0;
    for (int i = lane; i < n; i += 64)
        cnt += (box_ind[i] == wave);
    for (int off = 32; off; off >>= 1)
        cnt += __shfl_down(cnt, off);
    if (lane == 0) counts[wave] = cnt;
    __syncthreads();

    int start = 0;
    for (int i = 0; i < wave; ++i) start += counts[i];
    if (threadIdx.x == 0) {
        int acc = 0;
        for (int i = 0; i < NIMG; ++i) { offsets[i] = acc; acc += counts[i]; }
        offsets[NIMG] = acc;
    }

    int pos = start;
    for (int base = 0; base < n; base += 64) {
        const int i = base + lane;
        const bool m = (i < n) && (box_ind[i] == wave);
        const unsigned long long mask = __ballot(m);
        const int below = __popcll(mask & ((1ULL << lane) - 1ULL));
        if (m) order[pos + below] = i;
        pos += __popcll(mask);
    }
}

// ---- per-cell geometry (pixel indices, no lane folded in) -----------------
struct Cell {
    int p00, p01, p10, p11;   // pixel index y*W+x within image
    float wx, wy;
    bool valid;
    int oidx;                 // float4-granular output index (without lane)
};

__device__ __forceinline__ Cell cell_info(
    int c, const int* __restrict__ order, const f32x4* __restrict__ boxes4,
    int start)
{
    Cell k;
    const int bi = c / CROP_HW;
    const int r  = c - bi * CROP_HW;
    const int iy = r / 7;
    const int ix = r - iy * 7;
    const int b  = order[start + bi];

    const f32x4 bx = boxes4[b];   // {y1, x1, y2, x2}

    // reference order: step = (hi-lo)*(extent-1)/(n-1); s = lo*(extent-1)+i*step
    const float stepy = (bx.z - bx.x) * 63.0f / 6.0f;
    const float stepx = (bx.w - bx.y) * 63.0f / 6.0f;
    const float ys = bx.x * 63.0f + (float)iy * stepy;
    const float xs = bx.y * 63.0f + (float)ix * stepx;

    const float y0f = floorf(ys);
    const float x0f = floorf(xs);
    k.wy = ys - y0f;
    k.wx = xs - x0f;

    const int y0 = min(max((int)y0f, 0), H - 1);
    const int y1 = min(y0 + 1, H - 1);
    const int x0 = min(max((int)x0f, 0), W - 1);
    const int x1 = min(x0 + 1, W - 1);

    k.valid = (ys >= 0.0f) && (ys <= (float)(H - 1)) &&
              (xs >= 0.0f) && (xs <= (float)(W - 1));

    k.p00 = y0 * W + x0;
    k.p01 = y0 * W + x1;
    k.p10 = y1 * W + x0;
    k.p11 = y1 * W + x1;

    k.oidx = (b * CROP_HW + r) * (C / 4);   // max 12.5M, fits int
    return k;
}

// ---- kernel 2: XCD-partitioned crop, lane-parallel geometry ----------------
__global__ __launch_bounds__(256, 4) void crop_resize_xcd(
    const float* __restrict__ feats,
    const float* __restrict__ boxes,
    const int*   __restrict__ order,
    const int*   __restrict__ offsets,
    float*       __restrict__ out)
{
    const int img  = blockIdx.x & 7;     // block->XCD round-robin heuristic
    const int slot = blockIdx.x >> 3;
    const int lane = threadIdx.x & 63;
    const int wv   = threadIdx.x >> 6;   // 0..3

    const int start   = offsets[img];
    const int nb      = offsets[img + 1] - start;
    const int ncells  = nb * CROP_HW;
    const int ngroups = (ncells + G - 1) / G;
    const int wave_local = slot * 4 + wv;
    const int stride     = (gridDim.x >> 3) * 4;

    const f32x4* __restrict__ f4 = reinterpret_cast<const f32x4*>(feats)
                                   + (size_t)img * (H * W * (C / 4));
    const f32x4* __restrict__ boxes4 = reinterpret_cast<const f32x4*>(boxes);
    f32x4* __restrict__ o4 = reinterpret_cast<f32x4*>(out);

    for (int gi = wave_local; gi < ngroups; gi += stride) {
        const int cbase = gi * G;
        const int nval  = min(G, ncells - cbase);   // wave-uniform

        // phase A: lane computes geometry for cell cbase + (lane & 7);
        // lanes 8..63 duplicate lanes 0..7 (free in SIMT).
        int c = cbase + (lane & (G - 1));
        if (c > ncells - 1) c = ncells - 1;
        const Cell k = cell_info(c, order, boxes4, start);
        const unsigned long long vmask = __ballot(k.valid);

        // phase B: per cell j, broadcast params to SGPRs, gather, lerp, store.
        #pragma unroll
        for (int j = 0; j < G; ++j) {
            if (j >= nval) break;                      // wave-uniform
            const int   s00 = __builtin_amdgcn_readlane(k.p00, j);
            const int   s01 = __builtin_amdgcn_readlane(k.p01, j);
            const int   s10 = __builtin_amdgcn_readlane(k.p10, j);
            const int   s11 = __builtin_amdgcn_readlane(k.p11, j);
            const float swx = __uint_as_float(
                __builtin_amdgcn_readlane(__float_as_uint(k.wx), j));
            const float swy = __uint_as_float(
                __builtin_amdgcn_readlane(__float_as_uint(k.wy), j));
            const int   sox = __builtin_amdgcn_readlane(k.oidx, j);
            const bool  sval = (vmask >> j) & 1ULL;    // wave-uniform

            // wave-uniform pixel base + lane*16B: saddr-form loads
            const f32x4 v00 = f4[s00 * (C / 4) + lane];
            const f32x4 v01 = f4[s01 * (C / 4) + lane];
            const f32x4 v10 = f4[s10 * (C / 4) + lane];
            const f32x4 v11 = f4[s11 * (C / 4) + lane];

            // 4-weight bilinear (16 FMA): w00+w01+w10+w11 == 1
            const float w11 = swx * swy;
            const float w01 = swx - w11;       // wx*(1-wy)
            const float w10 = swy - w11;       // (1-wx)*wy
            const float w00 = 1.0f - swx - swy + w11;

            f32x4 res = v00 * w00;
            res += v01 * w01;
            res += v10 * w10;
            res += v11 * w11;
            if (!sval) res = (f32x4)0.0f;      // wave-uniform

            __builtin_nontemporal_store(res, &o4[sox + lane]);
        }
    }
}

extern "C" void kernel_launch(void* const* d_in, const int* in_sizes, int n_in,
                              void* d_out, int out_size, void* d_ws, size_t ws_size,
                              hipStream_t stream) {
    const float* feats   = (const float*)d_in[0];
    const float* boxes   = (const float*)d_in[1];
    const int*   box_ind = (const int*)d_in[2];
    float*       out     = (float*)d_out;

    const int n_boxes = in_sizes[1] / 4;

    int* order   = (int*)d_ws;            // n_boxes ints
    int* offsets = order + n_boxes;       // 9 ints

    bucket_kernel<<<1, 512, 0, stream>>>(box_ind, order, offsets, n_boxes);

    // 2048 blocks x 256 threads; 256 blocks (1024 waves) per image.
    crop_resize_xcd<<<2048, 256, 0, stream>>>(feats, boxes, order, offsets, out);
}